// Round 9
// baseline (2516.280 us; speedup 1.0000x reference)
//
#include <hip/hip_runtime.h>

typedef unsigned int u32;
typedef unsigned short u16;
typedef __bf16 bf16x8 __attribute__((ext_vector_type(8)));
typedef float f32x16 __attribute__((ext_vector_type(16)));
typedef float f32x4v __attribute__((ext_vector_type(4)));
typedef u32 u32x4 __attribute__((ext_vector_type(4)));
typedef u32 u32x2 __attribute__((ext_vector_type(2)));

#define BATCH    32768
#define DIN      256
#define UNITS    512
#define BM       64
#define NTHREADS 1024
#define NSTEP    6
#define DT       (1.0f/6.0f)
#define TANH_C   2.885390082f            // 2*log2(e), folded into Kp/Rp/bias
#define SMEM_BYTES (65536 + 65536 + 32768)   // heL + h1L + xkbL1 = 160KB

template <int E> struct IC { static constexpr int value = E; };

__device__ __forceinline__ u16 f2bf(float f) {
  return __builtin_bit_cast(u16, (__bf16)f);
}
__device__ __forceinline__ float bf2f(u16 b) {
  return __builtin_bit_cast(float, (u32)b << 16);
}
__device__ __forceinline__ u32 pk2(float a, float b) {
  return (u32)f2bf(a) | ((u32)f2bf(b) << 16);
}
// input is already 2*log2(e)*x (folded into weights)
__device__ __forceinline__ float tanh_pre(float t) {
  float tt = fminf(fmaxf(t, -60.f), 60.f);
  float a = __builtin_amdgcn_exp2f(tt);
  return (a - 1.f) * __builtin_amdgcn_rcpf(a + 1.f);
}

// Pack K (256x512) and R (512x512) f32 row-major into bf16 B-fragment order,
// PRE-SCALED by TANH_C. chunk c = g*512 + n holds rows g*8..g*8+7, col n.
__global__ void pack_weights(const float* __restrict__ Km, const float* __restrict__ Rm,
                             u16* __restrict__ Kp, u16* __restrict__ Rp) {
  int c = blockIdx.x * 256 + threadIdx.x;          // 0 .. 49151
  if (c < 32768) {
    int n = c & 511, g = c >> 9;                   // g < 64
    u32x4 p;
#pragma unroll
    for (int i = 0; i < 4; ++i) {
      u16 lo = f2bf(Rm[(g * 8 + 2 * i) * 512 + n] * TANH_C);
      u16 hh = f2bf(Rm[(g * 8 + 2 * i + 1) * 512 + n] * TANH_C);
      p[i] = (u32)lo | ((u32)hh << 16);
    }
    ((u32x4*)Rp)[c] = p;
  } else {
    int c2 = c - 32768;                            // < 16384
    int n = c2 & 511, g = c2 >> 9;                 // g < 32
    u32x4 p;
#pragma unroll
    for (int i = 0; i < 4; ++i) {
      u16 lo = f2bf(Km[(g * 8 + 2 * i) * 512 + n] * TANH_C);
      u16 hh = f2bf(Km[(g * 8 + 2 * i + 1) * 512 + n] * TANH_C);
      p[i] = (u32)lo | ((u32)hh << 16);
    }
    ((u32x4*)Kp)[c2] = p;
  }
}

__global__ __launch_bounds__(NTHREADS, 4)
void ctrnn_fused(const float* __restrict__ X, const float* __restrict__ H0,
                 const u16* __restrict__ Kp, const u16* __restrict__ Rp,
                 const float* __restrict__ bias, const float* __restrict__ scale,
                 float* __restrict__ out) {
  // heL   64KB: he bf16 [64 rows][512 cols], pitch 1024B, swizzle ^((m&7)<<4).
  //        Prologue stages x here first ([64][256] bf16, pitch 512B, same swizzle).
  // h1L   64KB: f32 h of row-tile1, [r][tid] per-thread-private slots.
  // xkbL1 32KB: packed-bf16 xkb of row-tile1, u32 [i][tid].
  extern __shared__ char smem[];
  char* heL  = smem;
  float* h1L = (float*)(smem + 65536);
  u32* xkbL1 = (u32*)(smem + 131072);

  const int tid  = threadIdx.x;
  const int lane = tid & 63;
  const int wv   = tid >> 6;             // 0..15 — wave owns cols [wv*32, wv*32+32)
  const int ln   = lane & 31, hi = lane >> 5;
  const long r0  = (long)blockIdx.x * BM;

  const int jc  = wv * 32 + ln;          // this thread's output column
  const int swA = (ln & 7) << 4;

  // stage x tile -> bf16 LDS [64][256], pitch 512B
  {
    const f32x4v* X4 = (const f32x4v*)(X + r0 * DIN);
#pragma unroll
    for (int i = 0; i < 4; ++i) {
      int flat = i * NTHREADS + tid;     // 0..4095 float4-chunks
      int m = flat >> 6, c4 = flat & 63;
      f32x4v v = X4[m * 64 + c4];
      u32x2 p;
      p.x = pk2(v.x, v.y);
      p.y = pk2(v.z, v.w);
      *(u32x2*)(heL + m * 512 + ((c4 * 8) ^ ((m & 7) << 4))) = p;
    }
  }

  const float scl = scale[jc];

  // load h: row-tile0 -> regs, row-tile1 -> h1L
  float h0[16];
#pragma unroll
  for (int r = 0; r < 16; ++r) {
    int m = (r & 3) + ((r >> 2) << 3) + hi * 4;
    h0[r] = H0[(r0 + m) * UNITS + jc];
    h1L[r * NTHREADS + tid] = H0[(r0 + m + 32) * UNITS + jc];
  }

  __syncthreads();

  // hoisted LDS address bases (all later accesses are base + immediate)
  int aBase[4], hB[4];
#pragma unroll
  for (int v = 0; v < 4; ++v) {
    aBase[v] = ln * 1024 + (((v * 32) | (hi * 16)) ^ swA);
    hB[v] = ((jc * 2) ^ ((hi * 4 + v) << 4)) + (hi * 4 + v) * 1024;
  }

  // ---- prologue: xkb = TANH_C*(x@K + b); both row-tiles share each B-frag ----
  u32 xkbP0[8];
  {
    f32x16 pre0, pre1;
    {
      float b = bias[jc] * TANH_C;
#pragma unroll
      for (int r = 0; r < 16; ++r) { pre0[r] = b; pre1[r] = b; }
    }
    const u32x4* Kp4 = (const u32x4*)Kp;
#pragma unroll
    for (int kb = 0; kb < 16; ++kb) {
      bf16x8 a0 = __builtin_bit_cast(bf16x8,
          *(const u32x4*)(heL + ln * 512        + (((kb * 32) | (hi * 16)) ^ swA)));
      bf16x8 a1 = __builtin_bit_cast(bf16x8,
          *(const u32x4*)(heL + (32 + ln) * 512 + (((kb * 32) | (hi * 16)) ^ swA)));
      bf16x8 bb = __builtin_bit_cast(bf16x8, Kp4[(kb * 2 + hi) * 512 + jc]);
      pre0 = __builtin_amdgcn_mfma_f32_32x32x16_bf16(a0, bb, pre0, 0, 0, 0);
      pre1 = __builtin_amdgcn_mfma_f32_32x32x16_bf16(a1, bb, pre1, 0, 0, 0);
    }
#pragma unroll
    for (int i = 0; i < 8; ++i) {
      xkbP0[i] = pk2(pre0[2 * i], pre0[2 * i + 1]);
      xkbL1[i * NTHREADS + tid] = pk2(pre1[2 * i], pre1[2 * i + 1]);
    }
  }
  __syncthreads();   // prologue x-reads + xkbL1 writes complete; heL -> he buffer

  // write he_1 = bf16(h), both tiles
#pragma unroll
  for (int r = 0; r < 16; ++r) {
    int off = hB[r & 3] + (r >> 2) * 8192;
    *(u16*)(heL + off)         = f2bf(h0[r]);
    *(u16*)(heL + off + 32768) = f2bf(h1L[r * NTHREADS + tid]);
  }
  __syncthreads();

  const u32x4* Rp4 = (const u32x4*)Rp;
  u32 accP0[8], accP1[8];

  // one RK4 sub-eval, ev known at compile time
  auto evalfn = [&](auto EVC, bool skipw) {
    constexpr int ev = decltype(EVC)::value;
    constexpr float wk  = (ev == 1 || ev == 2) ? 2.f : 1.f;
    constexpr float ce  = (ev < 2) ? (DT * 0.5f) : DT;
    constexpr float dt6 = DT / 6.f;

    // pre = xkb
    f32x16 p0, p1;
#pragma unroll
    for (int i = 0; i < 8; ++i) {
      u32 q0 = xkbP0[i];
      u32 q1 = xkbL1[i * NTHREADS + tid];
      p0[2 * i]     = __builtin_bit_cast(float, q0 << 16);
      p0[2 * i + 1] = __builtin_bit_cast(float, q0 & 0xffff0000u);
      p1[2 * i]     = __builtin_bit_cast(float, q1 << 16);
      p1[2 * i + 1] = __builtin_bit_cast(float, q1 & 0xffff0000u);
    }
    // K-loop: both row-tiles share each B-frag; all LDS addrs base+imm
#pragma unroll
    for (int kb = 0; kb < 32; ++kb) {
      bf16x8 a0 = __builtin_bit_cast(bf16x8,
          *(const u32x4*)(heL + aBase[kb & 3] + (kb >> 2) * 128));
      bf16x8 a1 = __builtin_bit_cast(bf16x8,
          *(const u32x4*)(heL + aBase[kb & 3] + (kb >> 2) * 128 + 32768));
      bf16x8 bb = __builtin_bit_cast(bf16x8, Rp4[(kb * 2 + hi) * 512 + jc]);
      p0 = __builtin_amdgcn_mfma_f32_32x32x16_bf16(a0, bb, p0, 0, 0, 0);
      p1 = __builtin_amdgcn_mfma_f32_32x32x16_bf16(a1, bb, p1, 0, 0, 0);
    }

    // pass1 tile0 (h in regs); stash he_next into p0
#pragma unroll
    for (int rp = 0; rp < 8; ++rp) {
      const int off = hB[(2 * rp) & 3] + (rp >> 1) * 8192;
      const int off1 = hB[((2 * rp) & 3) + 1] + (rp >> 1) * 8192;
      float he0 = bf2f(*(const u16*)(heL + off));
      float he1 = bf2f(*(const u16*)(heL + off1));
      float k0 = scl * tanh_pre(p0[2 * rp])     - he0;
      float k1 = scl * tanh_pre(p0[2 * rp + 1]) - he1;
      float a0, a1;
      if constexpr (ev == 0) { a0 = k0; a1 = k1; }
      else {
        a0 = bf2f((u16)(accP0[rp] & 0xffffu)) + wk * k0;
        a1 = bf2f((u16)(accP0[rp] >> 16))     + wk * k1;
      }
      if constexpr (ev == 3) {
        h0[2 * rp]     += dt6 * a0;
        h0[2 * rp + 1] += dt6 * a1;
        p0[2 * rp] = h0[2 * rp]; p0[2 * rp + 1] = h0[2 * rp + 1];
      } else {
        accP0[rp] = pk2(a0, a1);
        p0[2 * rp]     = h0[2 * rp]     + ce * k0;
        p0[2 * rp + 1] = h0[2 * rp + 1] + ce * k1;
      }
    }
    // pass1 tile1 (h in h1L); stash he_next into p1
#pragma unroll
    for (int rp = 0; rp < 8; ++rp) {
      const int off = hB[(2 * rp) & 3] + (rp >> 1) * 8192 + 32768;
      const int off1 = hB[((2 * rp) & 3) + 1] + (rp >> 1) * 8192 + 32768;
      float he0 = bf2f(*(const u16*)(heL + off));
      float he1 = bf2f(*(const u16*)(heL + off1));
      float k0 = scl * tanh_pre(p1[2 * rp])     - he0;
      float k1 = scl * tanh_pre(p1[2 * rp + 1]) - he1;
      float a0, a1;
      if constexpr (ev == 0) { a0 = k0; a1 = k1; }
      else {
        a0 = bf2f((u16)(accP1[rp] & 0xffffu)) + wk * k0;
        a1 = bf2f((u16)(accP1[rp] >> 16))     + wk * k1;
      }
      float hv0 = h1L[(2 * rp) * NTHREADS + tid];
      float hv1 = h1L[(2 * rp + 1) * NTHREADS + tid];
      if constexpr (ev == 3) {
        hv0 += dt6 * a0; hv1 += dt6 * a1;
        h1L[(2 * rp) * NTHREADS + tid]     = hv0;
        h1L[(2 * rp + 1) * NTHREADS + tid] = hv1;
        p1[2 * rp] = hv0; p1[2 * rp + 1] = hv1;
      } else {
        accP1[rp] = pk2(a0, a1);
        p1[2 * rp]     = hv0 + ce * k0;
        p1[2 * rp + 1] = hv1 + ce * k1;
      }
    }
    __syncthreads();   // all heL reads (A-frags + he_i) of this eval complete

    if (!skipw) {
      // pass2: store he_next (stashed in p0/p1) as bf16
#pragma unroll
      for (int r = 0; r < 16; ++r) {
        int off = hB[r & 3] + (r >> 2) * 8192;
        *(u16*)(heL + off)         = f2bf(p0[r]);
        *(u16*)(heL + off + 32768) = f2bf(p1[r]);
      }
      __syncthreads();   // he_{i+1} visible
    }
  };

#pragma unroll 1
  for (int step = 0; step < NSTEP; ++step) {
    evalfn(IC<0>{}, false);
    evalfn(IC<1>{}, false);
    evalfn(IC<2>{}, false);
    evalfn(IC<3>{}, step == NSTEP - 1);
  }

  // store final h: tile0 from regs, tile1 from h1L (own slots, no barrier needed)
#pragma unroll
  for (int r = 0; r < 16; ++r) {
    int m = (r & 3) + ((r >> 2) << 3) + hi * 4;
    out[(r0 + m) * UNITS + jc]      = h0[r];
    out[(r0 + m + 32) * UNITS + jc] = h1L[r * NTHREADS + tid];
  }
}

extern "C" void kernel_launch(void* const* d_in, const int* in_sizes, int n_in,
                              void* d_out, int out_size, void* d_ws, size_t ws_size,
                              hipStream_t stream) {
  const float* X     = (const float*)d_in[0];
  const float* H0    = (const float*)d_in[1];
  const float* Km    = (const float*)d_in[2];
  const float* Rm    = (const float*)d_in[3];
  const float* bias  = (const float*)d_in[4];
  const float* scale = (const float*)d_in[5];
  float* out = (float*)d_out;

  u16* Rp = (u16*)d_ws;                  // 512*512 bf16 = 512KB
  u16* Kp = Rp + UNITS * UNITS;          // 256*512 bf16 = 256KB

  (void)hipFuncSetAttribute((const void*)ctrnn_fused,
                            hipFuncAttributeMaxDynamicSharedMemorySize, SMEM_BYTES);

  pack_weights<<<192, 256, 0, stream>>>(Km, Rm, Kp, Rp);
  ctrnn_fused<<<BATCH / BM, NTHREADS, SMEM_BYTES, stream>>>(X, H0, Kp, Rp, bias, scale, out);
}

// Round 10
// 894.094 us; speedup vs baseline: 2.8143x; 2.8143x over previous
//
#include <hip/hip_runtime.h>

typedef unsigned int u32;
typedef unsigned short u16;
typedef __bf16 bf16x8 __attribute__((ext_vector_type(8)));
typedef float f32x16 __attribute__((ext_vector_type(16)));
typedef float f32x4v __attribute__((ext_vector_type(4)));
typedef u32 u32x4 __attribute__((ext_vector_type(4)));
typedef u32 u32x2 __attribute__((ext_vector_type(2)));

#define BATCH    32768
#define DIN      256
#define UNITS    512
#define BM       64
#define NTHREADS 1024
#define NSTEP    6
#define DT       (1.0f/6.0f)
#define TANH_C   2.885390082f            // 2*log2(e), folded into Kp/Rp/bias
#define SMEM_BYTES (65536 + 65536 + 32768)   // heL + h1L + xkbL1 = 160KB

template <int E> struct IC { static constexpr int value = E; };

__device__ __forceinline__ u16 f2bf(float f) {
  return __builtin_bit_cast(u16, (__bf16)f);
}
__device__ __forceinline__ float bf2f(u16 b) {
  return __builtin_bit_cast(float, (u32)b << 16);
}
__device__ __forceinline__ u32 pk2(float a, float b) {
  return (u32)f2bf(a) | ((u32)f2bf(b) << 16);
}
// input is already 2*log2(e)*x (folded into weights)
__device__ __forceinline__ float tanh_pre(float t) {
  float tt = fminf(fmaxf(t, -60.f), 60.f);
  float a = __builtin_amdgcn_exp2f(tt);
  return (a - 1.f) * __builtin_amdgcn_rcpf(a + 1.f);
}

// Pack K (256x512) and R (512x512) f32 row-major into bf16 B-fragment order,
// PRE-SCALED by TANH_C. chunk c = g*512 + n holds rows g*8..g*8+7, col n.
__global__ void pack_weights(const float* __restrict__ Km, const float* __restrict__ Rm,
                             u16* __restrict__ Kp, u16* __restrict__ Rp) {
  int c = blockIdx.x * 256 + threadIdx.x;          // 0 .. 49151
  if (c < 32768) {
    int n = c & 511, g = c >> 9;                   // g < 64
    u32x4 p;
#pragma unroll
    for (int i = 0; i < 4; ++i) {
      u16 lo = f2bf(Rm[(g * 8 + 2 * i) * 512 + n] * TANH_C);
      u16 hh = f2bf(Rm[(g * 8 + 2 * i + 1) * 512 + n] * TANH_C);
      p[i] = (u32)lo | ((u32)hh << 16);
    }
    ((u32x4*)Rp)[c] = p;
  } else {
    int c2 = c - 32768;                            // < 16384
    int n = c2 & 511, g = c2 >> 9;                 // g < 32
    u32x4 p;
#pragma unroll
    for (int i = 0; i < 4; ++i) {
      u16 lo = f2bf(Km[(g * 8 + 2 * i) * 512 + n] * TANH_C);
      u16 hh = f2bf(Km[(g * 8 + 2 * i + 1) * 512 + n] * TANH_C);
      p[i] = (u32)lo | ((u32)hh << 16);
    }
    ((u32x4*)Kp)[c2] = p;
  }
}

__global__ __launch_bounds__(NTHREADS, 4)
void ctrnn_fused(const float* __restrict__ X, const float* __restrict__ H0,
                 const u16* __restrict__ Kp, const u16* __restrict__ Rp,
                 const float* __restrict__ bias, const float* __restrict__ scale,
                 float* __restrict__ out) {
  // heL   64KB: he bf16 [64 rows][512 cols], pitch 1024B, swizzle ^((m&7)<<4).
  //        Prologue stages x here first ([64][256] bf16, pitch 512B, same swizzle).
  // h1L   64KB: f32 h of row-tile1, [r][tid] per-thread-private slots.
  // xkbL1 32KB: packed-bf16 xkb of row-tile1, u32 [i][tid].
  extern __shared__ char smem[];
  char* heL  = smem;
  float* h1L = (float*)(smem + 65536);
  u32* xkbL1 = (u32*)(smem + 131072);

  const int tid  = threadIdx.x;
  const int lane = tid & 63;
  const int wv   = tid >> 6;             // 0..15 — wave owns cols [wv*32, wv*32+32)
  const int ln   = lane & 31, hi = lane >> 5;
  const long r0  = (long)blockIdx.x * BM;

  const int jc  = wv * 32 + ln;          // this thread's output column
  const int swA = (ln & 7) << 4;

  // stage x tile -> bf16 LDS [64][256], pitch 512B
  {
    const f32x4v* X4 = (const f32x4v*)(X + r0 * DIN);
#pragma unroll
    for (int i = 0; i < 4; ++i) {
      int flat = i * NTHREADS + tid;     // 0..4095 float4-chunks
      int m = flat >> 6, c4 = flat & 63;
      f32x4v v = X4[m * 64 + c4];
      u32x2 p;
      p.x = pk2(v.x, v.y);
      p.y = pk2(v.z, v.w);
      *(u32x2*)(heL + m * 512 + ((c4 * 8) ^ ((m & 7) << 4))) = p;
    }
  }

  const float scl = scale[jc];

  // load h: row-tile0 -> regs, row-tile1 -> h1L
  float h0[16];
#pragma unroll
  for (int r = 0; r < 16; ++r) {
    int m = (r & 3) + ((r >> 2) << 3) + hi * 4;
    h0[r] = H0[(r0 + m) * UNITS + jc];
    h1L[r * NTHREADS + tid] = H0[(r0 + m + 32) * UNITS + jc];
  }

  __syncthreads();

  // hoisted LDS address bases (all later accesses are base + immediate)
  int aBase[4], hB[4];
#pragma unroll
  for (int v = 0; v < 4; ++v) {
    aBase[v] = ln * 1024 + (((v * 32) | (hi * 16)) ^ swA);
    hB[v] = ((jc * 2) ^ ((hi * 4 + v) << 4)) + (hi * 4 + v) * 1024;
  }

  // ---- prologue: xkb = TANH_C*(x@K + b); both row-tiles share each B-frag ----
  u32 xkbP0[8];
  {
    f32x16 pre0, pre1;
    {
      float b = bias[jc] * TANH_C;
#pragma unroll
      for (int r = 0; r < 16; ++r) { pre0[r] = b; pre1[r] = b; }
    }
    const u32x4* Kp4 = (const u32x4*)Kp;
#pragma unroll 2
    for (int kb = 0; kb < 16; ++kb) {
      bf16x8 a0 = __builtin_bit_cast(bf16x8,
          *(const u32x4*)(heL + ln * 512        + (((kb * 32) | (hi * 16)) ^ swA)));
      bf16x8 a1 = __builtin_bit_cast(bf16x8,
          *(const u32x4*)(heL + (32 + ln) * 512 + (((kb * 32) | (hi * 16)) ^ swA)));
      bf16x8 bb = __builtin_bit_cast(bf16x8, Kp4[(kb * 2 + hi) * 512 + jc]);
      pre0 = __builtin_amdgcn_mfma_f32_32x32x16_bf16(a0, bb, pre0, 0, 0, 0);
      pre1 = __builtin_amdgcn_mfma_f32_32x32x16_bf16(a1, bb, pre1, 0, 0, 0);
    }
#pragma unroll
    for (int i = 0; i < 8; ++i) {
      xkbP0[i] = pk2(pre0[2 * i], pre0[2 * i + 1]);
      xkbL1[i * NTHREADS + tid] = pk2(pre1[2 * i], pre1[2 * i + 1]);
    }
  }
  __syncthreads();   // prologue x-reads + xkbL1 writes complete; heL -> he buffer

  // write he_1 = bf16(h), both tiles
#pragma unroll
  for (int r = 0; r < 16; ++r) {
    int off = hB[r & 3] + (r >> 2) * 8192;
    *(u16*)(heL + off)         = f2bf(h0[r]);
    *(u16*)(heL + off + 32768) = f2bf(h1L[r * NTHREADS + tid]);
  }
  __syncthreads();

  const u32x4* Rp4 = (const u32x4*)Rp;
  u32 accP0[8], accP1[8];

  // one RK4 sub-eval, ev known at compile time
  auto evalfn = [&](auto EVC, bool skipw) {
    constexpr int ev = decltype(EVC)::value;
    constexpr float wk  = (ev == 1 || ev == 2) ? 2.f : 1.f;
    constexpr float ce  = (ev < 2) ? (DT * 0.5f) : DT;
    constexpr float dt6 = DT / 6.f;

    // pre = xkb
    f32x16 p0, p1;
#pragma unroll
    for (int i = 0; i < 8; ++i) {
      u32 q0 = xkbP0[i];
      u32 q1 = xkbL1[i * NTHREADS + tid];
      p0[2 * i]     = __builtin_bit_cast(float, q0 << 16);
      p0[2 * i + 1] = __builtin_bit_cast(float, q0 & 0xffff0000u);
      p1[2 * i]     = __builtin_bit_cast(float, q1 << 16);
      p1[2 * i + 1] = __builtin_bit_cast(float, q1 & 0xffff0000u);
    }
    // K-loop: both row-tiles share each B-frag; all LDS addrs base+imm.
    // unroll 2 ONLY: bounds in-flight loads (R9 full-unroll spilled 7.9GB).
#pragma unroll 2
    for (int kb = 0; kb < 32; ++kb) {
      bf16x8 a0 = __builtin_bit_cast(bf16x8,
          *(const u32x4*)(heL + aBase[kb & 3] + (kb >> 2) * 128));
      bf16x8 a1 = __builtin_bit_cast(bf16x8,
          *(const u32x4*)(heL + aBase[kb & 3] + (kb >> 2) * 128 + 32768));
      bf16x8 bb = __builtin_bit_cast(bf16x8, Rp4[(kb * 2 + hi) * 512 + jc]);
      p0 = __builtin_amdgcn_mfma_f32_32x32x16_bf16(a0, bb, p0, 0, 0, 0);
      p1 = __builtin_amdgcn_mfma_f32_32x32x16_bf16(a1, bb, p1, 0, 0, 0);
    }

    // pass1 tile0 (h in regs); stash he_next into p0
#pragma unroll
    for (int rp = 0; rp < 8; ++rp) {
      const int off = hB[(2 * rp) & 3] + (rp >> 1) * 8192;
      const int off1 = hB[((2 * rp) & 3) + 1] + (rp >> 1) * 8192;
      float he0 = bf2f(*(const u16*)(heL + off));
      float he1 = bf2f(*(const u16*)(heL + off1));
      float k0 = scl * tanh_pre(p0[2 * rp])     - he0;
      float k1 = scl * tanh_pre(p0[2 * rp + 1]) - he1;
      float a0, a1;
      if constexpr (ev == 0) { a0 = k0; a1 = k1; }
      else {
        a0 = bf2f((u16)(accP0[rp] & 0xffffu)) + wk * k0;
        a1 = bf2f((u16)(accP0[rp] >> 16))     + wk * k1;
      }
      if constexpr (ev == 3) {
        h0[2 * rp]     += dt6 * a0;
        h0[2 * rp + 1] += dt6 * a1;
        p0[2 * rp] = h0[2 * rp]; p0[2 * rp + 1] = h0[2 * rp + 1];
      } else {
        accP0[rp] = pk2(a0, a1);
        p0[2 * rp]     = h0[2 * rp]     + ce * k0;
        p0[2 * rp + 1] = h0[2 * rp + 1] + ce * k1;
      }
    }
    // pass1 tile1 (h in h1L); stash he_next into p1
#pragma unroll
    for (int rp = 0; rp < 8; ++rp) {
      const int off = hB[(2 * rp) & 3] + (rp >> 1) * 8192 + 32768;
      const int off1 = hB[((2 * rp) & 3) + 1] + (rp >> 1) * 8192 + 32768;
      float he0 = bf2f(*(const u16*)(heL + off));
      float he1 = bf2f(*(const u16*)(heL + off1));
      float k0 = scl * tanh_pre(p1[2 * rp])     - he0;
      float k1 = scl * tanh_pre(p1[2 * rp + 1]) - he1;
      float a0, a1;
      if constexpr (ev == 0) { a0 = k0; a1 = k1; }
      else {
        a0 = bf2f((u16)(accP1[rp] & 0xffffu)) + wk * k0;
        a1 = bf2f((u16)(accP1[rp] >> 16))     + wk * k1;
      }
      float hv0 = h1L[(2 * rp) * NTHREADS + tid];
      float hv1 = h1L[(2 * rp + 1) * NTHREADS + tid];
      if constexpr (ev == 3) {
        hv0 += dt6 * a0; hv1 += dt6 * a1;
        h1L[(2 * rp) * NTHREADS + tid]     = hv0;
        h1L[(2 * rp + 1) * NTHREADS + tid] = hv1;
        p1[2 * rp] = hv0; p1[2 * rp + 1] = hv1;
      } else {
        accP1[rp] = pk2(a0, a1);
        p1[2 * rp]     = hv0 + ce * k0;
        p1[2 * rp + 1] = hv1 + ce * k1;
      }
    }
    __syncthreads();   // all heL reads (A-frags + he_i) of this eval complete

    if (!skipw) {
      // pass2: store he_next (stashed in p0/p1) as bf16
#pragma unroll
      for (int r = 0; r < 16; ++r) {
        int off = hB[r & 3] + (r >> 2) * 8192;
        *(u16*)(heL + off)         = f2bf(p0[r]);
        *(u16*)(heL + off + 32768) = f2bf(p1[r]);
      }
      __syncthreads();   // he_{i+1} visible
    }
  };

#pragma unroll 1
  for (int step = 0; step < NSTEP; ++step) {
    evalfn(IC<0>{}, false);
    evalfn(IC<1>{}, false);
    evalfn(IC<2>{}, false);
    evalfn(IC<3>{}, step == NSTEP - 1);
  }

  // store final h: tile0 from regs, tile1 from h1L (own slots, no barrier needed)
#pragma unroll
  for (int r = 0; r < 16; ++r) {
    int m = (r & 3) + ((r >> 2) << 3) + hi * 4;
    out[(r0 + m) * UNITS + jc]      = h0[r];
    out[(r0 + m + 32) * UNITS + jc] = h1L[r * NTHREADS + tid];
  }
}

extern "C" void kernel_launch(void* const* d_in, const int* in_sizes, int n_in,
                              void* d_out, int out_size, void* d_ws, size_t ws_size,
                              hipStream_t stream) {
  const float* X     = (const float*)d_in[0];
  const float* H0    = (const float*)d_in[1];
  const float* Km    = (const float*)d_in[2];
  const float* Rm    = (const float*)d_in[3];
  const float* bias  = (const float*)d_in[4];
  const float* scale = (const float*)d_in[5];
  float* out = (float*)d_out;

  u16* Rp = (u16*)d_ws;                  // 512*512 bf16 = 512KB
  u16* Kp = Rp + UNITS * UNITS;          // 256*512 bf16 = 256KB

  (void)hipFuncSetAttribute((const void*)ctrnn_fused,
                            hipFuncAttributeMaxDynamicSharedMemorySize, SMEM_BYTES);

  pack_weights<<<192, 256, 0, stream>>>(Km, Rm, Kp, Rp);
  ctrnn_fused<<<BATCH / BM, NTHREADS, SMEM_BYTES, stream>>>(X, H0, Kp, Rp, bias, scale, out);
}

// Round 11
// 791.189 us; speedup vs baseline: 3.1804x; 1.1301x over previous
//
#include <hip/hip_runtime.h>

typedef unsigned int u32;
typedef unsigned short u16;
typedef __bf16 bf16x8 __attribute__((ext_vector_type(8)));
typedef float f32x16 __attribute__((ext_vector_type(16)));
typedef float f32x4v __attribute__((ext_vector_type(4)));
typedef u32 u32x4 __attribute__((ext_vector_type(4)));
typedef u32 u32x2 __attribute__((ext_vector_type(2)));

#define BATCH    32768
#define DIN      256
#define UNITS    512
#define BM       64
#define NTHREADS 1024
#define NSTEP    6
#define DT       (1.0f/6.0f)
#define TANH_C   2.885390082f            // 2*log2(e), folded into Kp/Rp/bias
#define SMEM_BYTES (65536 + 65536 + 32768)   // heL + h1L + xkbL1 = 160KB

template <int E> struct IC { static constexpr int value = E; };

__device__ __forceinline__ u16 f2bf(float f) {
  return __builtin_bit_cast(u16, (__bf16)f);
}
__device__ __forceinline__ float bf2f(u16 b) {
  return __builtin_bit_cast(float, (u32)b << 16);
}
__device__ __forceinline__ u32 pk2(float a, float b) {
  return (u32)f2bf(a) | ((u32)f2bf(b) << 16);
}
// input is already 2*log2(e)*x (folded into weights)
__device__ __forceinline__ float tanh_pre(float t) {
  float tt = fminf(fmaxf(t, -60.f), 60.f);
  float a = __builtin_amdgcn_exp2f(tt);
  return (a - 1.f) * __builtin_amdgcn_rcpf(a + 1.f);
}

// Pack K (256x512) and R (512x512) f32 row-major into bf16 B-fragment order,
// PRE-SCALED by TANH_C. chunk c = g*512 + n holds rows g*8..g*8+7, col n.
__global__ void pack_weights(const float* __restrict__ Km, const float* __restrict__ Rm,
                             u16* __restrict__ Kp, u16* __restrict__ Rp) {
  int c = blockIdx.x * 256 + threadIdx.x;          // 0 .. 49151
  if (c < 32768) {
    int n = c & 511, g = c >> 9;                   // g < 64
    u32x4 p;
#pragma unroll
    for (int i = 0; i < 4; ++i) {
      u16 lo = f2bf(Rm[(g * 8 + 2 * i) * 512 + n] * TANH_C);
      u16 hh = f2bf(Rm[(g * 8 + 2 * i + 1) * 512 + n] * TANH_C);
      p[i] = (u32)lo | ((u32)hh << 16);
    }
    ((u32x4*)Rp)[c] = p;
  } else {
    int c2 = c - 32768;                            // < 16384
    int n = c2 & 511, g = c2 >> 9;                 // g < 32
    u32x4 p;
#pragma unroll
    for (int i = 0; i < 4; ++i) {
      u16 lo = f2bf(Km[(g * 8 + 2 * i) * 512 + n] * TANH_C);
      u16 hh = f2bf(Km[(g * 8 + 2 * i + 1) * 512 + n] * TANH_C);
      p[i] = (u32)lo | ((u32)hh << 16);
    }
    ((u32x4*)Kp)[c2] = p;
  }
}

__global__ __launch_bounds__(NTHREADS, 4)
void ctrnn_fused(const float* __restrict__ X, const float* __restrict__ H0,
                 const u16* __restrict__ Kp, const u16* __restrict__ Rp,
                 const float* __restrict__ bias, const float* __restrict__ scale,
                 float* __restrict__ out) {
  // heL   64KB: he bf16 [64 rows][512 cols], pitch 1024B, swizzle ^((m&7)<<4).
  //        Prologue stages x here first ([64][256] bf16, pitch 512B, same swizzle).
  // h1L   64KB: f32 h of row-tile1, [r][tid] per-thread-private slots.
  // xkbL1 32KB: packed-bf16 xkb of row-tile1, u32 [i][tid].
  extern __shared__ char smem[];
  char* heL  = smem;
  float* h1L = (float*)(smem + 65536);
  u32* xkbL1 = (u32*)(smem + 131072);

  const int tid  = threadIdx.x;
  const int lane = tid & 63;
  const int wv   = tid >> 6;             // 0..15 — wave owns cols [wv*32, wv*32+32)
  const int ln   = lane & 31, hi = lane >> 5;
  const long r0  = (long)blockIdx.x * BM;

  const int jc  = wv * 32 + ln;          // this thread's output column
  const int swA = (ln & 7) << 4;

  // stage x tile -> bf16 LDS [64][256], pitch 512B
  {
    const f32x4v* X4 = (const f32x4v*)(X + r0 * DIN);
#pragma unroll
    for (int i = 0; i < 4; ++i) {
      int flat = i * NTHREADS + tid;     // 0..4095 float4-chunks
      int m = flat >> 6, c4 = flat & 63;
      f32x4v v = X4[m * 64 + c4];
      u32x2 p;
      p.x = pk2(v.x, v.y);
      p.y = pk2(v.z, v.w);
      *(u32x2*)(heL + m * 512 + ((c4 * 8) ^ ((m & 7) << 4))) = p;
    }
  }

  const float scl = scale[jc];

  // load h: row-tile0 -> regs, row-tile1 -> h1L
  float h0[16];
#pragma unroll
  for (int r = 0; r < 16; ++r) {
    int m = (r & 3) + ((r >> 2) << 3) + hi * 4;
    h0[r] = H0[(r0 + m) * UNITS + jc];
    h1L[r * NTHREADS + tid] = H0[(r0 + m + 32) * UNITS + jc];
  }

  __syncthreads();

  // ---- prologue: xkb = TANH_C*(x@K + b); both row-tiles share each B-frag ----
  u32 xkbP0[8];
  {
    f32x16 pre0, pre1;
    {
      float b = bias[jc] * TANH_C;
#pragma unroll
      for (int r = 0; r < 16; ++r) { pre0[r] = b; pre1[r] = b; }
    }
    const u32x4* Kp4 = (const u32x4*)Kp;
#pragma unroll 2
    for (int kb = 0; kb < 16; ++kb) {
      bf16x8 a0 = __builtin_bit_cast(bf16x8,
          *(const u32x4*)(heL + ln * 512        + (((kb * 32) | (hi * 16)) ^ swA)));
      bf16x8 a1 = __builtin_bit_cast(bf16x8,
          *(const u32x4*)(heL + (32 + ln) * 512 + (((kb * 32) | (hi * 16)) ^ swA)));
      bf16x8 bb = __builtin_bit_cast(bf16x8, Kp4[(kb * 2 + hi) * 512 + jc]);
      pre0 = __builtin_amdgcn_mfma_f32_32x32x16_bf16(a0, bb, pre0, 0, 0, 0);
      pre1 = __builtin_amdgcn_mfma_f32_32x32x16_bf16(a1, bb, pre1, 0, 0, 0);
    }
#pragma unroll
    for (int i = 0; i < 8; ++i) {
      xkbP0[i] = pk2(pre0[2 * i], pre0[2 * i + 1]);
      xkbL1[i * NTHREADS + tid] = pk2(pre1[2 * i], pre1[2 * i + 1]);
    }
  }
  __syncthreads();   // prologue x-reads + xkbL1 writes complete; heL -> he buffer

  // write he_1 = bf16(h), both tiles (R7 inline addressing)
#pragma unroll
  for (int r = 0; r < 16; ++r) {
    int m = (r & 3) + ((r >> 2) << 3) + hi * 4;
    *(u16*)(heL + m * 1024 + ((jc * 2) ^ ((m & 7) << 4))) = f2bf(h0[r]);
    int m1 = m + 32;
    *(u16*)(heL + m1 * 1024 + ((jc * 2) ^ ((m1 & 7) << 4))) = f2bf(h1L[r * NTHREADS + tid]);
  }
  __syncthreads();

  const u32x4* Rp4 = (const u32x4*)Rp;
  u32 accP0[8], accP1[8];

  // one RK4 sub-eval, ev known at compile time
  auto evalfn = [&](auto EVC, bool skipw) {
    constexpr int ev = decltype(EVC)::value;
    constexpr float wk  = (ev == 1 || ev == 2) ? 2.f : 1.f;
    constexpr float ce  = (ev < 2) ? (DT * 0.5f) : DT;
    constexpr float dt6 = DT / 6.f;

    // pre = xkb
    f32x16 p0, p1;
#pragma unroll
    for (int i = 0; i < 8; ++i) {
      u32 q0 = xkbP0[i];
      u32 q1 = xkbL1[i * NTHREADS + tid];
      p0[2 * i]     = __builtin_bit_cast(float, q0 << 16);
      p0[2 * i + 1] = __builtin_bit_cast(float, q0 & 0xffff0000u);
      p1[2 * i]     = __builtin_bit_cast(float, q1 << 16);
      p1[2 * i + 1] = __builtin_bit_cast(float, q1 & 0xffff0000u);
    }
    // K-loop: both row-tiles share each B-frag; unroll 2 ONLY (R9 lesson)
#pragma unroll 2
    for (int kb = 0; kb < 32; ++kb) {
      bf16x8 a0 = __builtin_bit_cast(bf16x8,
          *(const u32x4*)(heL + ln * 1024        + (((kb * 32) | (hi * 16)) ^ swA)));
      bf16x8 a1 = __builtin_bit_cast(bf16x8,
          *(const u32x4*)(heL + (32 + ln) * 1024 + (((kb * 32) | (hi * 16)) ^ swA)));
      bf16x8 bb = __builtin_bit_cast(bf16x8, Rp4[(kb * 2 + hi) * 512 + jc]);
      p0 = __builtin_amdgcn_mfma_f32_32x32x16_bf16(a0, bb, p0, 0, 0, 0);
      p1 = __builtin_amdgcn_mfma_f32_32x32x16_bf16(a1, bb, p1, 0, 0, 0);
    }

    // pass1 tile0 (h in regs); stash he_next into p0
#pragma unroll
    for (int rp = 0; rp < 8; ++rp) {
      int m0 = ((2 * rp) & 3) + (((2 * rp) >> 2) << 3) + hi * 4;
      int m1 = ((2 * rp + 1) & 3) + (((2 * rp + 1) >> 2) << 3) + hi * 4;
      float he0 = bf2f(*(const u16*)(heL + m0 * 1024 + ((jc * 2) ^ ((m0 & 7) << 4))));
      float he1 = bf2f(*(const u16*)(heL + m1 * 1024 + ((jc * 2) ^ ((m1 & 7) << 4))));
      float k0 = scl * tanh_pre(p0[2 * rp])     - he0;
      float k1 = scl * tanh_pre(p0[2 * rp + 1]) - he1;
      float a0, a1;
      if constexpr (ev == 0) { a0 = k0; a1 = k1; }
      else {
        a0 = bf2f((u16)(accP0[rp] & 0xffffu)) + wk * k0;
        a1 = bf2f((u16)(accP0[rp] >> 16))     + wk * k1;
      }
      if constexpr (ev == 3) {
        h0[2 * rp]     += dt6 * a0;
        h0[2 * rp + 1] += dt6 * a1;
        p0[2 * rp] = h0[2 * rp]; p0[2 * rp + 1] = h0[2 * rp + 1];
      } else {
        accP0[rp] = pk2(a0, a1);
        p0[2 * rp]     = h0[2 * rp]     + ce * k0;
        p0[2 * rp + 1] = h0[2 * rp + 1] + ce * k1;
      }
    }
    // pass1 tile1 (h in h1L); stash he_next into p1
#pragma unroll
    for (int rp = 0; rp < 8; ++rp) {
      int m0 = ((2 * rp) & 3) + (((2 * rp) >> 2) << 3) + hi * 4 + 32;
      int m1 = ((2 * rp + 1) & 3) + (((2 * rp + 1) >> 2) << 3) + hi * 4 + 32;
      float he0 = bf2f(*(const u16*)(heL + m0 * 1024 + ((jc * 2) ^ ((m0 & 7) << 4))));
      float he1 = bf2f(*(const u16*)(heL + m1 * 1024 + ((jc * 2) ^ ((m1 & 7) << 4))));
      float k0 = scl * tanh_pre(p1[2 * rp])     - he0;
      float k1 = scl * tanh_pre(p1[2 * rp + 1]) - he1;
      float a0, a1;
      if constexpr (ev == 0) { a0 = k0; a1 = k1; }
      else {
        a0 = bf2f((u16)(accP1[rp] & 0xffffu)) + wk * k0;
        a1 = bf2f((u16)(accP1[rp] >> 16))     + wk * k1;
      }
      float hv0 = h1L[(2 * rp) * NTHREADS + tid];
      float hv1 = h1L[(2 * rp + 1) * NTHREADS + tid];
      if constexpr (ev == 3) {
        hv0 += dt6 * a0; hv1 += dt6 * a1;
        h1L[(2 * rp) * NTHREADS + tid]     = hv0;
        h1L[(2 * rp + 1) * NTHREADS + tid] = hv1;
        p1[2 * rp] = hv0; p1[2 * rp + 1] = hv1;
      } else {
        accP1[rp] = pk2(a0, a1);
        p1[2 * rp]     = hv0 + ce * k0;
        p1[2 * rp + 1] = hv1 + ce * k1;
      }
    }
    __syncthreads();   // all heL reads (A-frags + he_i) of this eval complete

    if (!skipw) {
      // pass2: store he_next (stashed in p0/p1) as bf16
#pragma unroll
      for (int r = 0; r < 16; ++r) {
        int m = (r & 3) + ((r >> 2) << 3) + hi * 4;
        *(u16*)(heL + m * 1024 + ((jc * 2) ^ ((m & 7) << 4))) = f2bf(p0[r]);
        int m1 = m + 32;
        *(u16*)(heL + m1 * 1024 + ((jc * 2) ^ ((m1 & 7) << 4))) = f2bf(p1[r]);
      }
      __syncthreads();   // he_{i+1} visible
    }
  };

#pragma unroll 1
  for (int step = 0; step < NSTEP; ++step) {
    evalfn(IC<0>{}, false);
    evalfn(IC<1>{}, false);
    evalfn(IC<2>{}, false);
    evalfn(IC<3>{}, step == NSTEP - 1);
  }

  // store final h: tile0 from regs, tile1 from h1L (own slots, no barrier needed)
#pragma unroll
  for (int r = 0; r < 16; ++r) {
    int m = (r & 3) + ((r >> 2) << 3) + hi * 4;
    out[(r0 + m) * UNITS + jc]      = h0[r];
    out[(r0 + m + 32) * UNITS + jc] = h1L[r * NTHREADS + tid];
  }
}

extern "C" void kernel_launch(void* const* d_in, const int* in_sizes, int n_in,
                              void* d_out, int out_size, void* d_ws, size_t ws_size,
                              hipStream_t stream) {
  const float* X     = (const float*)d_in[0];
  const float* H0    = (const float*)d_in[1];
  const float* Km    = (const float*)d_in[2];
  const float* Rm    = (const float*)d_in[3];
  const float* bias  = (const float*)d_in[4];
  const float* scale = (const float*)d_in[5];
  float* out = (float*)d_out;

  u16* Rp = (u16*)d_ws;                  // 512*512 bf16 = 512KB
  u16* Kp = Rp + UNITS * UNITS;          // 256*512 bf16 = 256KB

  (void)hipFuncSetAttribute((const void*)ctrnn_fused,
                            hipFuncAttributeMaxDynamicSharedMemorySize, SMEM_BYTES);

  pack_weights<<<192, 256, 0, stream>>>(Km, Rm, Kp, Rp);
  ctrnn_fused<<<BATCH / BM, NTHREADS, SMEM_BYTES, stream>>>(X, H0, Kp, Rp, bias, scale, out);
}

// Round 12
// 673.782 us; speedup vs baseline: 3.7346x; 1.1742x over previous
//
#include <hip/hip_runtime.h>

typedef unsigned int u32;
typedef unsigned short u16;
typedef __bf16 bf16x8 __attribute__((ext_vector_type(8)));
typedef float f32x16 __attribute__((ext_vector_type(16)));
typedef float f32x4v __attribute__((ext_vector_type(4)));
typedef u32 u32x4 __attribute__((ext_vector_type(4)));
typedef u32 u32x2 __attribute__((ext_vector_type(2)));

#define BATCH    32768
#define DIN      256
#define UNITS    512
#define BM       64
#define NTHREADS 1024
#define NSTEP    6
#define DT       (1.0f/6.0f)
#define TANH_C   2.885390082f            // 2*log2(e), folded into Kp/Rp/bias
#define SMEM_BYTES (65536 + 65536 + 32768)   // heL + h1L + xkbL1 = 160KB

__device__ __forceinline__ u16 f2bf(float f) {
  return __builtin_bit_cast(u16, (__bf16)f);
}
__device__ __forceinline__ float bf2f(u16 b) {
  return __builtin_bit_cast(float, (u32)b << 16);
}
__device__ __forceinline__ u32 pk2(float a, float b) {
  return (u32)f2bf(a) | ((u32)f2bf(b) << 16);
}
// arg is pre-scaled by 2*log2(e); tanh = 1 - 2/(2^t + 1)
__device__ __forceinline__ float tanh_pre(float t) {
  float a = __builtin_amdgcn_exp2f(fminf(t, 60.f));
  float r = __builtin_amdgcn_rcpf(a + 1.f);
  return __builtin_fmaf(-2.f, r, 1.f);
}

// Pack K (256x512) and R (512x512) f32 row-major into bf16 B-fragment order,
// PRE-SCALED by TANH_C. chunk c = g*512 + n holds rows g*8..g*8+7, col n.
__global__ void pack_weights(const float* __restrict__ Km, const float* __restrict__ Rm,
                             u16* __restrict__ Kp, u16* __restrict__ Rp) {
  int c = blockIdx.x * 256 + threadIdx.x;          // 0 .. 49151
  if (c < 32768) {
    int n = c & 511, g = c >> 9;                   // g < 64
    u32x4 p;
#pragma unroll
    for (int i = 0; i < 4; ++i) {
      u16 lo = f2bf(Rm[(g * 8 + 2 * i) * 512 + n] * TANH_C);
      u16 hh = f2bf(Rm[(g * 8 + 2 * i + 1) * 512 + n] * TANH_C);
      p[i] = (u32)lo | ((u32)hh << 16);
    }
    ((u32x4*)Rp)[c] = p;
  } else {
    int c2 = c - 32768;                            // < 16384
    int n = c2 & 511, g = c2 >> 9;                 // g < 32
    u32x4 p;
#pragma unroll
    for (int i = 0; i < 4; ++i) {
      u16 lo = f2bf(Km[(g * 8 + 2 * i) * 512 + n] * TANH_C);
      u16 hh = f2bf(Km[(g * 8 + 2 * i + 1) * 512 + n] * TANH_C);
      p[i] = (u32)lo | ((u32)hh << 16);
    }
    ((u32x4*)Kp)[c2] = p;
  }
}

__global__ __launch_bounds__(NTHREADS, 4)
void ctrnn_fused(const float* __restrict__ X, const float* __restrict__ H0,
                 const u16* __restrict__ Kp, const u16* __restrict__ Rp,
                 const float* __restrict__ bias, const float* __restrict__ scale,
                 float* __restrict__ out) {
  // heL   64KB: he bf16 [64 rows][512 cols], pitch 1024B, swizzle ^((m&7)<<4).
  //        Prologue stages x here first ([64][256] bf16, pitch 512B, same swizzle).
  // h1L   64KB: f32 h of row-tile1, [r][tid] per-thread-private slots.
  // xkbL1 32KB: packed-bf16 xkb of row-tile1, u32 [i][tid].
  extern __shared__ char smem[];
  char* heL  = smem;
  float* h1L = (float*)(smem + 65536);
  u32* xkbL1 = (u32*)(smem + 131072);

  const int tid  = threadIdx.x;
  const int lane = tid & 63;
  const int wv   = tid >> 6;             // 0..15 — wave owns cols [wv*32, wv*32+32)
  const int ln   = lane & 31, hi = lane >> 5;
  const long r0  = (long)blockIdx.x * BM;

  const int jc  = wv * 32 + ln;          // this thread's output column
  const int swA = (ln & 7) << 4;

  // stage x tile -> bf16 LDS [64][256], pitch 512B
  {
    const f32x4v* X4 = (const f32x4v*)(X + r0 * DIN);
#pragma unroll
    for (int i = 0; i < 4; ++i) {
      int flat = i * NTHREADS + tid;     // 0..4095 float4-chunks
      int m = flat >> 6, c4 = flat & 63;
      f32x4v v = X4[m * 64 + c4];
      u32x2 p;
      p.x = pk2(v.x, v.y);
      p.y = pk2(v.z, v.w);
      *(u32x2*)(heL + m * 512 + ((c4 * 8) ^ ((m & 7) << 4))) = p;
    }
  }

  const float scl = scale[jc];

  // load h: row-tile0 -> regs, row-tile1 -> h1L (disjoint from heL x-region)
  float h0[16];
#pragma unroll
  for (int r = 0; r < 16; ++r) {
    int m = (r & 3) + ((r >> 2) << 3) + hi * 4;
    h0[r] = H0[(r0 + m) * UNITS + jc];
    h1L[r * NTHREADS + tid] = H0[(r0 + m + 32) * UNITS + jc];
  }

  __syncthreads();

  // ---- prologue: xkb = TANH_C*(x@K + b); both row-tiles share each B-frag ----
  {
    f32x16 pre0, pre1;
    {
      float b = bias[jc] * TANH_C;
#pragma unroll
      for (int r = 0; r < 16; ++r) { pre0[r] = b; pre1[r] = b; }
    }
    const u32x4* Kp4 = (const u32x4*)Kp;
#pragma unroll 2
    for (int kb = 0; kb < 16; ++kb) {
      bf16x8 a0 = __builtin_bit_cast(bf16x8,
          *(const u32x4*)(heL + ln * 512        + (((kb * 32) | (hi * 16)) ^ swA)));
      bf16x8 a1 = __builtin_bit_cast(bf16x8,
          *(const u32x4*)(heL + (32 + ln) * 512 + (((kb * 32) | (hi * 16)) ^ swA)));
      bf16x8 bb = __builtin_bit_cast(bf16x8, Kp4[(kb * 2 + hi) * 512 + jc]);
      pre0 = __builtin_amdgcn_mfma_f32_32x32x16_bf16(a0, bb, pre0, 0, 0, 0);
      pre1 = __builtin_amdgcn_mfma_f32_32x32x16_bf16(a1, bb, pre1, 0, 0, 0);
    }
    u32 xkbP0t[8];
#pragma unroll
    for (int i = 0; i < 8; ++i) {
      xkbP0t[i] = pk2(pre0[2 * i], pre0[2 * i + 1]);
      xkbL1[i * NTHREADS + tid] = pk2(pre1[2 * i], pre1[2 * i + 1]);
    }
    __syncthreads();   // prologue x-reads + xkbL1 writes complete; heL -> he buffer

    // write he_1 = bf16(h) for both tiles
#pragma unroll
    for (int r = 0; r < 16; ++r) {
      int m = (r & 3) + ((r >> 2) << 3) + hi * 4;
      *(u16*)(heL + m * 1024        + ((jc * 2) ^ ((m & 7) << 4)))        = f2bf(h0[r]);
      int m1 = m + 32;
      *(u16*)(heL + m1 * 1024       + ((jc * 2) ^ ((m1 & 7) << 4)))       = f2bf(h1L[r * NTHREADS + tid]);
    }
    __syncthreads();

    const u32x4* Rp4 = (const u32x4*)Rp;
    u32 accP0[8], accP1[8];
    u32 xkbP0[8];
#pragma unroll
    for (int i = 0; i < 8; ++i) xkbP0[i] = xkbP0t[i];

#pragma unroll 1
    for (int it = 0; it < NSTEP * 4; ++it) {
      const int ev = it & 3;
      const float wk = (ev == 1 || ev == 2) ? 2.f : 1.f;
      const float ce = (ev < 2) ? (DT * 0.5f) : DT;
      const bool ev0 = (ev == 0), ev3 = (ev == 3);
      const bool last = (it == NSTEP * 4 - 1);

      // pre init: tile0 from regs, tile1 from xkbL1
      f32x16 p0, p1;
#pragma unroll
      for (int i = 0; i < 8; ++i) {
        u32 q0 = xkbP0[i];
        u32 q1 = xkbL1[i * NTHREADS + tid];
        p0[2 * i]     = bf2f((u16)(q0 & 0xffffu));
        p0[2 * i + 1] = bf2f((u16)(q0 >> 16));
        p1[2 * i]     = bf2f((u16)(q1 & 0xffffu));
        p1[2 * i + 1] = bf2f((u16)(q1 >> 16));
      }
      // K-loop: both row-tiles share each B-frag (one L2 fetch per kb)
#pragma unroll 2
      for (int kb = 0; kb < 32; ++kb) {
        bf16x8 a0 = __builtin_bit_cast(bf16x8,
            *(const u32x4*)(heL + ln * 1024        + (((kb * 32) | (hi * 16)) ^ swA)));
        bf16x8 a1 = __builtin_bit_cast(bf16x8,
            *(const u32x4*)(heL + (32 + ln) * 1024 + (((kb * 32) | (hi * 16)) ^ swA)));
        bf16x8 bb = __builtin_bit_cast(bf16x8, Rp4[(kb * 2 + hi) * 512 + jc]);
        p0 = __builtin_amdgcn_mfma_f32_32x32x16_bf16(a0, bb, p0, 0, 0, 0);
        p1 = __builtin_amdgcn_mfma_f32_32x32x16_bf16(a1, bb, p1, 0, 0, 0);
      }

      // epilogue tile0 (h in regs); stash k into p0
#pragma unroll
      for (int rp = 0; rp < 8; ++rp) {
        int m0 = ((2 * rp) & 3) + (((2 * rp) >> 2) << 3) + hi * 4;
        int m1 = ((2 * rp + 1) & 3) + (((2 * rp + 1) >> 2) << 3) + hi * 4;
        float he0 = bf2f(*(const u16*)(heL + m0 * 1024 + ((jc * 2) ^ ((m0 & 7) << 4))));
        float he1 = bf2f(*(const u16*)(heL + m1 * 1024 + ((jc * 2) ^ ((m1 & 7) << 4))));
        float k0 = __builtin_fmaf(scl, tanh_pre(p0[2 * rp]),     -he0);
        float k1 = __builtin_fmaf(scl, tanh_pre(p0[2 * rp + 1]), -he1);
        float a0 = (ev0 ? 0.f : bf2f((u16)(accP0[rp] & 0xffffu))) + wk * k0;
        float a1 = (ev0 ? 0.f : bf2f((u16)(accP0[rp] >> 16)))     + wk * k1;
        if (ev3) {
          h0[2 * rp]     += (DT / 6.f) * a0;
          h0[2 * rp + 1] += (DT / 6.f) * a1;
        } else {
          accP0[rp] = pk2(a0, a1);
        }
        p0[2 * rp] = k0; p0[2 * rp + 1] = k1;
      }
      // epilogue tile1 (h in h1L); stash k into p1
#pragma unroll
      for (int rp = 0; rp < 8; ++rp) {
        int m0 = ((2 * rp) & 3) + (((2 * rp) >> 2) << 3) + hi * 4 + 32;
        int m1 = ((2 * rp + 1) & 3) + (((2 * rp + 1) >> 2) << 3) + hi * 4 + 32;
        float he0 = bf2f(*(const u16*)(heL + m0 * 1024 + ((jc * 2) ^ ((m0 & 7) << 4))));
        float he1 = bf2f(*(const u16*)(heL + m1 * 1024 + ((jc * 2) ^ ((m1 & 7) << 4))));
        float k0 = __builtin_fmaf(scl, tanh_pre(p1[2 * rp]),     -he0);
        float k1 = __builtin_fmaf(scl, tanh_pre(p1[2 * rp + 1]), -he1);
        float a0 = (ev0 ? 0.f : bf2f((u16)(accP1[rp] & 0xffffu))) + wk * k0;
        float a1 = (ev0 ? 0.f : bf2f((u16)(accP1[rp] >> 16)))     + wk * k1;
        if (ev3) {
          float hv0 = h1L[(2 * rp) * NTHREADS + tid]     + (DT / 6.f) * a0;
          float hv1 = h1L[(2 * rp + 1) * NTHREADS + tid] + (DT / 6.f) * a1;
          h1L[(2 * rp) * NTHREADS + tid]     = hv0;
          h1L[(2 * rp + 1) * NTHREADS + tid] = hv1;
        } else {
          accP1[rp] = pk2(a0, a1);
        }
        p1[2 * rp] = k0; p1[2 * rp + 1] = k1;
      }
      __syncthreads();   // all heL reads (A-frags + he_i) of this eval complete

      if (!last) {
        // write he_next = (ev3) ? h : h + ce*k  (k stashed in p0/p1)
#pragma unroll
        for (int r = 0; r < 16; ++r) {
          int m = (r & 3) + ((r >> 2) << 3) + hi * 4;
          float v0 = ev3 ? h0[r] : h0[r] + ce * p0[r];
          *(u16*)(heL + m * 1024 + ((jc * 2) ^ ((m & 7) << 4))) = f2bf(v0);
          int m1 = m + 32;
          float hv = h1L[r * NTHREADS + tid];
          float v1 = ev3 ? hv : hv + ce * p1[r];
          *(u16*)(heL + m1 * 1024 + ((jc * 2) ^ ((m1 & 7) << 4))) = f2bf(v1);
        }
        __syncthreads();   // he_{i+1} visible
      }
    }
  }

  // store final h: tile0 from regs, tile1 from h1L
#pragma unroll
  for (int r = 0; r < 16; ++r) {
    int m = (r & 3) + ((r >> 2) << 3) + hi * 4;
    out[(r0 + m) * UNITS + jc]      = h0[r];
    out[(r0 + m + 32) * UNITS + jc] = h1L[r * NTHREADS + tid];
  }
}

extern "C" void kernel_launch(void* const* d_in, const int* in_sizes, int n_in,
                              void* d_out, int out_size, void* d_ws, size_t ws_size,
                              hipStream_t stream) {
  const float* X     = (const float*)d_in[0];
  const float* H0    = (const float*)d_in[1];
  const float* Km    = (const float*)d_in[2];
  const float* Rm    = (const float*)d_in[3];
  const float* bias  = (const float*)d_in[4];
  const float* scale = (const float*)d_in[5];
  float* out = (float*)d_out;

  u16* Rp = (u16*)d_ws;                  // 512*512 bf16 = 512KB
  u16* Kp = Rp + UNITS * UNITS;          // 256*512 bf16 = 256KB

  (void)hipFuncSetAttribute((const void*)ctrnn_fused,
                            hipFuncAttributeMaxDynamicSharedMemorySize, SMEM_BYTES);

  pack_weights<<<192, 256, 0, stream>>>(Km, Rm, Kp, Rp);
  ctrnn_fused<<<BATCH / BM, NTHREADS, SMEM_BYTES, stream>>>(X, H0, Kp, Rp, bias, scale, out);
}